// Round 10
// baseline (720.961 us; speedup 1.0000x reference)
//
#include <hip/hip_runtime.h>

#define DD 128
#define SCATTER_REP 12   // measurement: idempotent, rep'd for rocprof visibility
#define APPLY_REP   8    // measurement: idempotent, rep'd for rocprof visibility

typedef float vfloat4 __attribute__((ext_vector_type(4)));

__device__ inline float4 ntload4(const float* p) {
    vfloat4 v = __builtin_nontemporal_load(reinterpret_cast<const vfloat4*>(p));
    return make_float4(v.x, v.y, v.z, v.w);
}

// ---------------------------------------------------------------------------
// K1: per-node dots s[n]=h·aw_src, t[n]=h·aw_dst + attn_b; zeroes count[n].
// Tail blocks (>= n_node_blocks) instead transpose W -> Wt (one dispatch less).
// ---------------------------------------------------------------------------
__global__ __launch_bounds__(256) void k_node_dots(
    const float* __restrict__ h, const float* __restrict__ attn_w,
    const float* __restrict__ attn_b,
    float* __restrict__ s, float* __restrict__ t,
    int* __restrict__ count, int n_nodes, int n_node_blocks,
    const float* __restrict__ W, float* __restrict__ Wt)
{
    if (blockIdx.x >= n_node_blocks) {
        int idx = (blockIdx.x - n_node_blocks) * 256 + threadIdx.x;
        if (idx < 128 * 256) {
            int k = idx >> 8;          // 0..127
            int q = idx & 255;         // 0..255
            Wt[q * 128 + k] = W[idx];
        }
        return;
    }
    int gid  = blockIdx.x * blockDim.x + threadIdx.x;
    int node = gid >> 6;
    int lane = threadIdx.x & 63;
    if (node >= n_nodes) return;
    const float2 hv = *reinterpret_cast<const float2*>(h + (size_t)node * DD + lane * 2);
    const float2 as = *reinterpret_cast<const float2*>(attn_w + lane * 2);
    const float2 ad = *reinterpret_cast<const float2*>(attn_w + DD + lane * 2);
    float sa = hv.x * as.x + hv.y * as.y;
    float ta = hv.x * ad.x + hv.y * ad.y;
    #pragma unroll
    for (int off = 32; off > 0; off >>= 1) {
        sa += __shfl_down(sa, off);
        ta += __shfl_down(ta, off);
    }
    if (lane == 0) { s[node] = sa; t[node] = ta + attn_b[0]; count[node] = 0; }
}

// ---------------------------------------------------------------------------
// K2: histogram + per-edge rank (native int atomics)
// ---------------------------------------------------------------------------
__global__ __launch_bounds__(256) void k_hist(
    const int* __restrict__ dst, int* __restrict__ count,
    int* __restrict__ rank, int n_edges)
{
    int e = blockIdx.x * blockDim.x + threadIdx.x;
    if (e >= n_edges) return;
    rank[e] = atomicAdd(count + dst[e], 1);
}

// ---------------------------------------------------------------------------
// K3a: per-block partial sums of count
// ---------------------------------------------------------------------------
__global__ __launch_bounds__(256) void k_scan_bsum(
    const int* __restrict__ count, int* __restrict__ bsum, int n)
{
    __shared__ int sm[256];
    int tid = threadIdx.x;
    int idx = blockIdx.x * 256 + tid;
    int v = (idx < n) ? count[idx] : 0;
    sm[tid] = v; __syncthreads();
    for (int off = 128; off > 0; off >>= 1) {
        if (tid < off) sm[tid] += sm[tid + off];
        __syncthreads();
    }
    if (tid == 0) bsum[blockIdx.x] = sm[0];
}

// ---------------------------------------------------------------------------
// K3b: offsets in one pass — every block redundantly scans the (<=256)
// block sums in LDS, picks its own base, then scans its 256 counts.
// ---------------------------------------------------------------------------
__global__ __launch_bounds__(256) void k_scan_apply(
    const int* __restrict__ count, const int* __restrict__ bsum, int nb,
    int* __restrict__ offset, int n, int n_edges)
{
    __shared__ int sb[256];
    __shared__ int sm[256];
    int tid = threadIdx.x;
    int v = (tid < nb) ? bsum[tid] : 0;
    sb[tid] = v; __syncthreads();
    for (int off = 1; off < 256; off <<= 1) {
        int t2 = (tid >= off) ? sb[tid - off] : 0;
        __syncthreads();
        sb[tid] += t2;
        __syncthreads();
    }
    int boff = (blockIdx.x == 0) ? 0 : sb[blockIdx.x - 1];
    int idx = blockIdx.x * 256 + tid;
    int c = (idx < n) ? count[idx] : 0;
    sm[tid] = c; __syncthreads();
    for (int off = 1; off < 256; off <<= 1) {
        int t2 = (tid >= off) ? sm[tid - off] : 0;
        __syncthreads();
        sm[tid] += t2;
        __syncthreads();
    }
    if (idx < n) offset[idx] = boff + sm[tid] - c;
    if (idx == 0) offset[n] = n_edges;
}

// ---------------------------------------------------------------------------
// K4: scatter {edge id, relu score} as ONE int2 into dst-sorted position.
// (t_buf already contains t + attn_b.)  Idempotent -> rep'd for measurement.
// ---------------------------------------------------------------------------
__global__ __launch_bounds__(256) void k_scatter_ids(
    const int* __restrict__ dst, const int* __restrict__ src,
    const int* __restrict__ rank, const int* __restrict__ offset,
    const float* __restrict__ s, const float* __restrict__ t,
    int2* __restrict__ os, int n_edges)
{
    int e = blockIdx.x * blockDim.x + threadIdx.x;
    if (e >= n_edges) return;
    for (int rep = 0; rep < SCATTER_REP; ++rep) {
        int d   = dst[e];
        int pos = offset[d] + rank[e];
        float sc = fmaxf(s[src[e]] + t[d], 0.f);
        int2 v; v.x = e; v.y = __float_as_int(sc);
        os[pos] = v;
        asm volatile("" ::: "memory");   // keep reps live
    }
}

// ---------------------------------------------------------------------------
// K5: fused per-node attention (measured ~64 us, at HBM roofline).
// ---------------------------------------------------------------------------
__global__ __launch_bounds__(256) void k_fused(
    const int* __restrict__ offset, const int2* __restrict__ os,
    const float* __restrict__ ef,
    float* __restrict__ u, int n_nodes)
{
    int node = blockIdx.x * (blockDim.x >> 6) + (threadIdx.x >> 6);
    int lane = threadIdx.x & 63;
    if (node >= n_nodes) return;
    int beg = offset[node];
    int deg = offset[node + 1] - beg;

    if (deg <= 64) {
        int2 os_l = make_int2(0, 0);
        if (lane < deg) os_l = os[beg + lane];
        int   e_l = os_l.x;
        float pe  = (lane < deg) ? expf(__int_as_float(os_l.y)) : 0.f;
        float sum = pe;
        #pragma unroll
        for (int off = 32; off > 0; off >>= 1) sum += __shfl_xor(sum, off);
        float inv  = sum > 0.f ? 1.f / sum : 0.f;
        float pw_l = pe * inv;

        int grp = lane >> 3, sub = lane & 7;
        float4 a0 = make_float4(0.f, 0.f, 0.f, 0.f);
        float4 a1 = a0, a2 = a0, a3 = a0;
        int kmax = (deg + 7) >> 3;
        for (int k = 0; k < kmax; ++k) {
            int j  = grp + 8 * k;
            int jj = (j < deg) ? j : 0;
            int   e  = __shfl(e_l, jj);
            float pw = __shfl(pw_l, jj);
            if (j < deg) {
                const float* er = ef + (size_t)e * DD;
                float4 v0 = ntload4(er + sub * 4);
                float4 v1 = ntload4(er + 32 + sub * 4);
                float4 v2 = ntload4(er + 64 + sub * 4);
                float4 v3 = ntload4(er + 96 + sub * 4);
                a0.x = fmaf(pw, v0.x, a0.x); a0.y = fmaf(pw, v0.y, a0.y);
                a0.z = fmaf(pw, v0.z, a0.z); a0.w = fmaf(pw, v0.w, a0.w);
                a1.x = fmaf(pw, v1.x, a1.x); a1.y = fmaf(pw, v1.y, a1.y);
                a1.z = fmaf(pw, v1.z, a1.z); a1.w = fmaf(pw, v1.w, a1.w);
                a2.x = fmaf(pw, v2.x, a2.x); a2.y = fmaf(pw, v2.y, a2.y);
                a2.z = fmaf(pw, v2.z, a2.z); a2.w = fmaf(pw, v2.w, a2.w);
                a3.x = fmaf(pw, v3.x, a3.x); a3.y = fmaf(pw, v3.y, a3.y);
                a3.z = fmaf(pw, v3.z, a3.z); a3.w = fmaf(pw, v3.w, a3.w);
            }
        }
        #pragma unroll
        for (int off = 8; off <= 32; off <<= 1) {
            a0.x += __shfl_xor(a0.x, off); a0.y += __shfl_xor(a0.y, off);
            a0.z += __shfl_xor(a0.z, off); a0.w += __shfl_xor(a0.w, off);
            a1.x += __shfl_xor(a1.x, off); a1.y += __shfl_xor(a1.y, off);
            a1.z += __shfl_xor(a1.z, off); a1.w += __shfl_xor(a1.w, off);
            a2.x += __shfl_xor(a2.x, off); a2.y += __shfl_xor(a2.y, off);
            a2.z += __shfl_xor(a2.z, off); a2.w += __shfl_xor(a2.w, off);
            a3.x += __shfl_xor(a3.x, off); a3.y += __shfl_xor(a3.y, off);
            a3.z += __shfl_xor(a3.z, off); a3.w += __shfl_xor(a3.w, off);
        }
        if (lane < 8) {
            float4* ur = reinterpret_cast<float4*>(u + (size_t)node * DD);
            ur[sub]      = a0;
            ur[8 + sub]  = a1;
            ur[16 + sub] = a2;
            ur[24 + sub] = a3;
        }
    } else {
        float sum = 0.f;
        for (int i = lane; i < deg; i += 64) {
            int2 v = os[beg + i];
            sum += expf(__int_as_float(v.y));
        }
        #pragma unroll
        for (int off = 32; off > 0; off >>= 1) sum += __shfl_xor(sum, off);
        float inv = sum > 0.f ? 1.f / sum : 0.f;

        float2 acc = make_float2(0.f, 0.f);
        for (int i0 = 0; i0 < deg; i0 += 64) {
            int cnt = min(64, deg - i0);
            int2 v = make_int2(0, 0);
            if (lane < cnt) v = os[beg + i0 + lane];
            int   e_l = v.x;
            float p_l = (lane < cnt) ? expf(__int_as_float(v.y)) * inv : 0.f;
            for (int j = 0; j < cnt; ++j) {
                int   e  = __shfl(e_l, j);
                float pw = __shfl(p_l, j);
                float2 vv = *reinterpret_cast<const float2*>(ef + (size_t)e * DD + lane * 2);
                acc.x = fmaf(pw, vv.x, acc.x);
                acc.y = fmaf(pw, vv.y, acc.y);
            }
        }
        *reinterpret_cast<float2*>(u + (size_t)node * DD + lane * 2) = acc;
    }
}

// ---------------------------------------------------------------------------
// K6: out[n] = relu([h[n], z[n]] @ W^T + b) via transposed Wt.
// Idempotent -> rep'd for measurement.
// ---------------------------------------------------------------------------
__global__ __launch_bounds__(256) void k_apply(
    const float* __restrict__ h, const float* __restrict__ u,
    const float* __restrict__ Wt, const float* __restrict__ b,
    float* __restrict__ out, int n_nodes)
{
    __shared__ float4 hz[16][64];   // 16 nodes x 256 floats (h | z)
    int n0  = blockIdx.x * 16;
    int tid = threadIdx.x;
    #pragma unroll
    for (int it = 0; it < 4; ++it) {
        int idx = tid + it * 256;
        int n   = idx >> 6;
        int q   = idx & 63;
        int node = n0 + n;
        float4 v = make_float4(0.f, 0.f, 0.f, 0.f);
        if (node < n_nodes) {
            if (q < 32) v = *reinterpret_cast<const float4*>(h + (size_t)node * DD + q * 4);
            else        v = *reinterpret_cast<const float4*>(u + (size_t)node * DD + (q - 32) * 4);
        }
        hz[n][q] = v;
    }
    __syncthreads();

    int k = tid & 127;
    int g = tid >> 7;
    for (int rep = 0; rep < APPLY_REP; ++rep) {
        float acc[8] = {0.f, 0.f, 0.f, 0.f, 0.f, 0.f, 0.f, 0.f};
        const float* wt = Wt + k;
        #pragma unroll 4
        for (int q4 = 0; q4 < 64; ++q4) {
            float w0 = wt[(q4 * 4 + 0) * 128];
            float w1 = wt[(q4 * 4 + 1) * 128];
            float w2 = wt[(q4 * 4 + 2) * 128];
            float w3 = wt[(q4 * 4 + 3) * 128];
            #pragma unroll
            for (int i = 0; i < 8; ++i) {
                float4 x = hz[g * 8 + i][q4];
                acc[i] = fmaf(w0, x.x, fmaf(w1, x.y, fmaf(w2, x.z, fmaf(w3, x.w, acc[i]))));
            }
        }
        float bk = b[k];
        #pragma unroll
        for (int i = 0; i < 8; ++i) {
            int node = n0 + g * 8 + i;
            if (node < n_nodes)
                out[(size_t)node * DD + k] = fmaxf(acc[i] + bk, 0.f);
        }
        asm volatile("" ::: "memory");   // keep reps live
    }
}

// ---------------------------------------------------------------------------
extern "C" void kernel_launch(void* const* d_in, const int* in_sizes, int n_in,
                              void* d_out, int out_size, void* d_ws, size_t ws_size,
                              hipStream_t stream)
{
    const float* nfeats = (const float*)d_in[0];
    const float* efeats = (const float*)d_in[1];
    const float* W      = (const float*)d_in[2];
    const float* Wb     = (const float*)d_in[3];
    const float* attn_w = (const float*)d_in[4];
    const float* attn_b = (const float*)d_in[5];
    const int*   src    = (const int*)d_in[6];
    const int*   dst    = (const int*)d_in[7];

    const int n_nodes = in_sizes[0] / DD;
    const int n_edges = in_sizes[6];
    const int NB = (n_nodes + 255) / 256;     // scan blocks (196 <= 256)
    const int NDB = (n_nodes + 3) / 4;        // node-dot blocks

    // workspace layout (os_buf 8B-aligned)
    char* wsb = (char*)d_ws;
    float* s_buf  = (float*)wsb;                         wsb += (size_t)n_nodes * 4;
    float* t_buf  = (float*)wsb;                         wsb += (size_t)n_nodes * 4;
    int*   count  = (int*)wsb;                           wsb += (size_t)n_nodes * 4;
    int*   offset = (int*)wsb;                           wsb += (size_t)(n_nodes + 2) * 4;
    int*   bsum   = (int*)wsb;                           wsb += (size_t)256 * 4;
    int2*  os_buf = (int2*)wsb;                          wsb += (size_t)n_edges * 8;
    float* wt_buf = (float*)wsb;                         wsb += (size_t)256 * 128 * 4;
    float* u_buf  = (float*)wsb;                         // N*128 f32
    int*   rank   = (int*)u_buf;                         // aliased: dead before u written

    k_node_dots<<<NDB + 128, 256, 0, stream>>>(nfeats, attn_w, attn_b, s_buf, t_buf,
                                               count, n_nodes, NDB, W, wt_buf);
    k_hist<<<(n_edges + 255) / 256, 256, 0, stream>>>(dst, count, rank, n_edges);
    k_scan_bsum<<<NB, 256, 0, stream>>>(count, bsum, n_nodes);
    k_scan_apply<<<NB, 256, 0, stream>>>(count, bsum, NB, offset, n_nodes, n_edges);
    k_scatter_ids<<<(n_edges + 255) / 256, 256, 0, stream>>>(dst, src, rank, offset,
                                                             s_buf, t_buf,
                                                             os_buf, n_edges);

    k_fused<<<(n_nodes + 3) / 4, 256, 0, stream>>>(offset, os_buf, efeats, u_buf, n_nodes);

    k_apply<<<(n_nodes + 15) / 16, 256, 0, stream>>>(nfeats, u_buf, wt_buf, Wb,
                                                     (float*)d_out, n_nodes);
}

// Round 11
// 192.968 us; speedup vs baseline: 3.7362x; 3.7362x over previous
//
#include <hip/hip_runtime.h>

#define DD 128

typedef float vfloat4 __attribute__((ext_vector_type(4)));
typedef __attribute__((ext_vector_type(8))) short short8;   // 8 bf16 = 4 VGPRs
typedef __attribute__((ext_vector_type(4))) float f32x4;    // MFMA accumulator

__device__ inline float4 ntload4(const float* p) {
    vfloat4 v = __builtin_nontemporal_load(reinterpret_cast<const vfloat4*>(p));
    return make_float4(v.x, v.y, v.z, v.w);
}

// round-to-nearest-even f32 -> bf16 (as ushort)
__device__ inline ushort f2bf(float f) {
    unsigned x = __float_as_uint(f);
    return (ushort)((x + 0x7FFFu + ((x >> 16) & 1u)) >> 16);
}

// ---------------------------------------------------------------------------
// K1: per-node dots s[n]=h·aw_src, t[n]=h·aw_dst+attn_b; zeroes count[n];
// writes h16 (bf16 copy of h). Tail blocks cast W -> W16 (row-major, no
// transpose: MFMA B-fragments read W[col][k] contiguous in k).
// ---------------------------------------------------------------------------
__global__ __launch_bounds__(256) void k_node_dots(
    const float* __restrict__ h, const float* __restrict__ attn_w,
    const float* __restrict__ attn_b,
    float* __restrict__ s, float* __restrict__ t,
    int* __restrict__ count, ushort* __restrict__ h16,
    int n_nodes, int n_node_blocks,
    const float* __restrict__ W, ushort* __restrict__ W16)
{
    if (blockIdx.x >= n_node_blocks) {
        int idx = (blockIdx.x - n_node_blocks) * 256 + threadIdx.x;
        if (idx < 128 * 256) W16[idx] = f2bf(W[idx]);
        return;
    }
    int gid  = blockIdx.x * blockDim.x + threadIdx.x;
    int node = gid >> 6;
    int lane = threadIdx.x & 63;
    if (node >= n_nodes) return;
    const float2 hv = *reinterpret_cast<const float2*>(h + (size_t)node * DD + lane * 2);
    const float2 as = *reinterpret_cast<const float2*>(attn_w + lane * 2);
    const float2 ad = *reinterpret_cast<const float2*>(attn_w + DD + lane * 2);
    ushort2 hb; hb.x = f2bf(hv.x); hb.y = f2bf(hv.y);
    *reinterpret_cast<ushort2*>(h16 + (size_t)node * DD + lane * 2) = hb;
    float sa = hv.x * as.x + hv.y * as.y;
    float ta = hv.x * ad.x + hv.y * ad.y;
    #pragma unroll
    for (int off = 32; off > 0; off >>= 1) {
        sa += __shfl_down(sa, off);
        ta += __shfl_down(ta, off);
    }
    if (lane == 0) { s[node] = sa; t[node] = ta + attn_b[0]; count[node] = 0; }
}

// ---------------------------------------------------------------------------
// K2: histogram + per-edge rank (native int atomics)
// ---------------------------------------------------------------------------
__global__ __launch_bounds__(256) void k_hist(
    const int* __restrict__ dst, int* __restrict__ count,
    int* __restrict__ rank, int n_edges)
{
    int e = blockIdx.x * blockDim.x + threadIdx.x;
    if (e >= n_edges) return;
    rank[e] = atomicAdd(count + dst[e], 1);
}

// ---------------------------------------------------------------------------
// K3a: per-block partial sums of count
// ---------------------------------------------------------------------------
__global__ __launch_bounds__(256) void k_scan_bsum(
    const int* __restrict__ count, int* __restrict__ bsum, int n)
{
    __shared__ int sm[256];
    int tid = threadIdx.x;
    int idx = blockIdx.x * 256 + tid;
    int v = (idx < n) ? count[idx] : 0;
    sm[tid] = v; __syncthreads();
    for (int off = 128; off > 0; off >>= 1) {
        if (tid < off) sm[tid] += sm[tid + off];
        __syncthreads();
    }
    if (tid == 0) bsum[blockIdx.x] = sm[0];
}

// ---------------------------------------------------------------------------
// K3b: offsets in one pass (redundant block-sum scan per block; nb <= 256)
// ---------------------------------------------------------------------------
__global__ __launch_bounds__(256) void k_scan_apply(
    const int* __restrict__ count, const int* __restrict__ bsum, int nb,
    int* __restrict__ offset, int n, int n_edges)
{
    __shared__ int sb[256];
    __shared__ int sm[256];
    int tid = threadIdx.x;
    int v = (tid < nb) ? bsum[tid] : 0;
    sb[tid] = v; __syncthreads();
    for (int off = 1; off < 256; off <<= 1) {
        int t2 = (tid >= off) ? sb[tid - off] : 0;
        __syncthreads();
        sb[tid] += t2;
        __syncthreads();
    }
    int boff = (blockIdx.x == 0) ? 0 : sb[blockIdx.x - 1];
    int idx = blockIdx.x * 256 + tid;
    int c = (idx < n) ? count[idx] : 0;
    sm[tid] = c; __syncthreads();
    for (int off = 1; off < 256; off <<= 1) {
        int t2 = (tid >= off) ? sm[tid - off] : 0;
        __syncthreads();
        sm[tid] += t2;
        __syncthreads();
    }
    if (idx < n) offset[idx] = boff + sm[tid] - c;
    if (idx == 0) offset[n] = n_edges;
}

// ---------------------------------------------------------------------------
// K4: scatter {edge id, relu score} as ONE int2 into dst-sorted position
// ---------------------------------------------------------------------------
__global__ __launch_bounds__(256) void k_scatter_ids(
    const int* __restrict__ dst, const int* __restrict__ src,
    const int* __restrict__ rank, const int* __restrict__ offset,
    const float* __restrict__ s, const float* __restrict__ t,
    int2* __restrict__ os, int n_edges)
{
    int e = blockIdx.x * blockDim.x + threadIdx.x;
    if (e >= n_edges) return;
    int d   = dst[e];
    int pos = offset[d] + rank[e];
    float sc = fmaxf(s[src[e]] + t[d], 0.f);
    int2 v; v.x = e; v.y = __float_as_int(sc);
    os[pos] = v;
}

// ---------------------------------------------------------------------------
// K5: fused per-node attention (measured ~64 us, HBM roofline).
// Writes z normalized as bf16 (u16) — feeds the MFMA apply directly.
// ---------------------------------------------------------------------------
__global__ __launch_bounds__(256) void k_fused(
    const int* __restrict__ offset, const int2* __restrict__ os,
    const float* __restrict__ ef,
    ushort* __restrict__ u16, int n_nodes)
{
    int node = blockIdx.x * (blockDim.x >> 6) + (threadIdx.x >> 6);
    int lane = threadIdx.x & 63;
    if (node >= n_nodes) return;
    int beg = offset[node];
    int deg = offset[node + 1] - beg;

    if (deg <= 64) {
        int2 os_l = make_int2(0, 0);
        if (lane < deg) os_l = os[beg + lane];
        int   e_l = os_l.x;
        float pe  = (lane < deg) ? expf(__int_as_float(os_l.y)) : 0.f;
        float sum = pe;
        #pragma unroll
        for (int off = 32; off > 0; off >>= 1) sum += __shfl_xor(sum, off);
        float inv  = sum > 0.f ? 1.f / sum : 0.f;
        float pw_l = pe * inv;

        int grp = lane >> 3, sub = lane & 7;
        float4 a0 = make_float4(0.f, 0.f, 0.f, 0.f);
        float4 a1 = a0, a2 = a0, a3 = a0;
        int kmax = (deg + 7) >> 3;
        for (int k = 0; k < kmax; ++k) {
            int j  = grp + 8 * k;
            int jj = (j < deg) ? j : 0;
            int   e  = __shfl(e_l, jj);
            float pw = __shfl(pw_l, jj);
            if (j < deg) {
                const float* er = ef + (size_t)e * DD;
                float4 v0 = ntload4(er + sub * 4);
                float4 v1 = ntload4(er + 32 + sub * 4);
                float4 v2 = ntload4(er + 64 + sub * 4);
                float4 v3 = ntload4(er + 96 + sub * 4);
                a0.x = fmaf(pw, v0.x, a0.x); a0.y = fmaf(pw, v0.y, a0.y);
                a0.z = fmaf(pw, v0.z, a0.z); a0.w = fmaf(pw, v0.w, a0.w);
                a1.x = fmaf(pw, v1.x, a1.x); a1.y = fmaf(pw, v1.y, a1.y);
                a1.z = fmaf(pw, v1.z, a1.z); a1.w = fmaf(pw, v1.w, a1.w);
                a2.x = fmaf(pw, v2.x, a2.x); a2.y = fmaf(pw, v2.y, a2.y);
                a2.z = fmaf(pw, v2.z, a2.z); a2.w = fmaf(pw, v2.w, a2.w);
                a3.x = fmaf(pw, v3.x, a3.x); a3.y = fmaf(pw, v3.y, a3.y);
                a3.z = fmaf(pw, v3.z, a3.z); a3.w = fmaf(pw, v3.w, a3.w);
            }
        }
        #pragma unroll
        for (int off = 8; off <= 32; off <<= 1) {
            a0.x += __shfl_xor(a0.x, off); a0.y += __shfl_xor(a0.y, off);
            a0.z += __shfl_xor(a0.z, off); a0.w += __shfl_xor(a0.w, off);
            a1.x += __shfl_xor(a1.x, off); a1.y += __shfl_xor(a1.y, off);
            a1.z += __shfl_xor(a1.z, off); a1.w += __shfl_xor(a1.w, off);
            a2.x += __shfl_xor(a2.x, off); a2.y += __shfl_xor(a2.y, off);
            a2.z += __shfl_xor(a2.z, off); a2.w += __shfl_xor(a2.w, off);
            a3.x += __shfl_xor(a3.x, off); a3.y += __shfl_xor(a3.y, off);
            a3.z += __shfl_xor(a3.z, off); a3.w += __shfl_xor(a3.w, off);
        }
        if (lane < 8) {
            ushort* ur = u16 + (size_t)node * DD;
            *reinterpret_cast<ushort4*>(ur + 4 * sub) =
                make_ushort4(f2bf(a0.x), f2bf(a0.y), f2bf(a0.z), f2bf(a0.w));
            *reinterpret_cast<ushort4*>(ur + 32 + 4 * sub) =
                make_ushort4(f2bf(a1.x), f2bf(a1.y), f2bf(a1.z), f2bf(a1.w));
            *reinterpret_cast<ushort4*>(ur + 64 + 4 * sub) =
                make_ushort4(f2bf(a2.x), f2bf(a2.y), f2bf(a2.z), f2bf(a2.w));
            *reinterpret_cast<ushort4*>(ur + 96 + 4 * sub) =
                make_ushort4(f2bf(a3.x), f2bf(a3.y), f2bf(a3.z), f2bf(a3.w));
        }
    } else {
        float sum = 0.f;
        for (int i = lane; i < deg; i += 64) {
            int2 v = os[beg + i];
            sum += expf(__int_as_float(v.y));
        }
        #pragma unroll
        for (int off = 32; off > 0; off >>= 1) sum += __shfl_xor(sum, off);
        float inv = sum > 0.f ? 1.f / sum : 0.f;

        float2 acc = make_float2(0.f, 0.f);
        for (int i0 = 0; i0 < deg; i0 += 64) {
            int cnt = min(64, deg - i0);
            int2 v = make_int2(0, 0);
            if (lane < cnt) v = os[beg + i0 + lane];
            int   e_l = v.x;
            float p_l = (lane < cnt) ? expf(__int_as_float(v.y)) * inv : 0.f;
            for (int j = 0; j < cnt; ++j) {
                int   e  = __shfl(e_l, j);
                float pw = __shfl(p_l, j);
                float2 vv = *reinterpret_cast<const float2*>(ef + (size_t)e * DD + lane * 2);
                acc.x = fmaf(pw, vv.x, acc.x);
                acc.y = fmaf(pw, vv.y, acc.y);
            }
        }
        ushort2 uu; uu.x = f2bf(acc.x); uu.y = f2bf(acc.y);
        *reinterpret_cast<ushort2*>(u16 + (size_t)node * DD + lane * 2) = uu;
    }
}

// ---------------------------------------------------------------------------
// K6: out = relu([h16|u16] @ W16^T + b) via bf16 MFMA (f32 accumulate).
// Wave = 16 nodes x 128 cols: 8 K-chunks x 8 col-tiles of 16x16x32 MFMA.
// A-frag: lane(row=l&15, quad=l>>4) reads 8 bf16 at X[node][kc*32+quad*8]
// straight from global (16 lanes cover 16 rows' 64B lines fully). B-frag:
// lane(col=l&15) reads W16[col][kc*32+quad*8] — contiguous, L1/L2-hot.
// D layout: col=lane&15, row=(lane>>4)*4+reg [guide §3, m89-verified].
// ---------------------------------------------------------------------------
__global__ __launch_bounds__(256) void k_apply_mfma(
    const ushort* __restrict__ h16, const ushort* __restrict__ u16,
    const ushort* __restrict__ W16, const float* __restrict__ b,
    float* __restrict__ out, int n_nodes)
{
    int wave = threadIdx.x >> 6;
    int lane = threadIdx.x & 63;
    int nodeBase = blockIdx.x * 64 + wave * 16;
    int row  = lane & 15;
    int quad = lane >> 4;
    int node = nodeBase + row;
    if (node >= n_nodes) node = n_nodes - 1;   // clamp loads; stores guarded

    f32x4 acc[8];
    #pragma unroll
    for (int ct = 0; ct < 8; ++ct) acc[ct] = (f32x4){0.f, 0.f, 0.f, 0.f};

    #pragma unroll
    for (int kc = 0; kc < 8; ++kc) {
        const ushort* abase = (kc < 4)
            ? (h16 + (size_t)node * DD + kc * 32 + quad * 8)
            : (u16 + (size_t)node * DD + (kc - 4) * 32 + quad * 8);
        short8 a = *reinterpret_cast<const short8*>(abase);
        #pragma unroll
        for (int ct = 0; ct < 8; ++ct) {
            const ushort* wb = W16 + ((size_t)(ct * 16 + row)) * 256 + kc * 32 + quad * 8;
            short8 bb = *reinterpret_cast<const short8*>(wb);
            acc[ct] = __builtin_amdgcn_mfma_f32_16x16x32_bf16(a, bb, acc[ct], 0, 0, 0);
        }
    }

    #pragma unroll
    for (int ct = 0; ct < 8; ++ct) {
        int col = ct * 16 + row;
        float bk = b[col];
        #pragma unroll
        for (int r = 0; r < 4; ++r) {
            int n = nodeBase + quad * 4 + r;
            if (n < n_nodes)
                out[(size_t)n * DD + col] = fmaxf(acc[ct][r] + bk, 0.f);
        }
    }
}

// ---------------------------------------------------------------------------
extern "C" void kernel_launch(void* const* d_in, const int* in_sizes, int n_in,
                              void* d_out, int out_size, void* d_ws, size_t ws_size,
                              hipStream_t stream)
{
    const float* nfeats = (const float*)d_in[0];
    const float* efeats = (const float*)d_in[1];
    const float* W      = (const float*)d_in[2];
    const float* Wb     = (const float*)d_in[3];
    const float* attn_w = (const float*)d_in[4];
    const float* attn_b = (const float*)d_in[5];
    const int*   src    = (const int*)d_in[6];
    const int*   dst    = (const int*)d_in[7];

    const int n_nodes = in_sizes[0] / DD;
    const int n_edges = in_sizes[6];
    const int NB  = (n_nodes + 255) / 256;    // scan blocks (196 <= 256)
    const int NDB = (n_nodes + 3) / 4;        // node-dot blocks

    // workspace layout (os_buf 8B-aligned; all segments 4B-multiple)
    char* wsb = (char*)d_ws;
    float*  s_buf  = (float*)wsb;                        wsb += (size_t)n_nodes * 4;
    float*  t_buf  = (float*)wsb;                        wsb += (size_t)n_nodes * 4;
    int*    count  = (int*)wsb;                          wsb += (size_t)n_nodes * 4;
    int*    offset = (int*)wsb;                          wsb += (size_t)(n_nodes + 2) * 4;
    int*    bsum   = (int*)wsb;                          wsb += (size_t)256 * 4;
    int2*   os_buf = (int2*)wsb;                         wsb += (size_t)n_edges * 8;
    ushort* h16    = (ushort*)wsb;                       wsb += (size_t)n_nodes * DD * 2;
    ushort* u16    = (ushort*)wsb;                       wsb += (size_t)n_nodes * DD * 2;
    ushort* W16    = (ushort*)wsb;                       wsb += (size_t)128 * 256 * 2;
    int*    rank   = (int*)u16;   // aliased: rank dead before k_fused writes u16

    k_node_dots<<<NDB + 128, 256, 0, stream>>>(nfeats, attn_w, attn_b, s_buf, t_buf,
                                               count, h16, n_nodes, NDB, W, W16);
    k_hist<<<(n_edges + 255) / 256, 256, 0, stream>>>(dst, count, rank, n_edges);
    k_scan_bsum<<<NB, 256, 0, stream>>>(count, bsum, n_nodes);
    k_scan_apply<<<NB, 256, 0, stream>>>(count, bsum, NB, offset, n_nodes, n_edges);
    k_scatter_ids<<<(n_edges + 255) / 256, 256, 0, stream>>>(dst, src, rank, offset,
                                                             s_buf, t_buf,
                                                             os_buf, n_edges);

    k_fused<<<(n_nodes + 3) / 4, 256, 0, stream>>>(offset, os_buf, efeats, u16, n_nodes);

    k_apply_mfma<<<(n_nodes + 63) / 64, 256, 0, stream>>>(h16, u16, W16, Wb,
                                                          (float*)d_out, n_nodes);
}